// Round 12
// baseline (314.186 us; speedup 1.0000x reference)
//
#include <hip/hip_runtime.h>
#include <hip/hip_bf16.h>
#include <math.h>

// Problem constants (fixed by setup_inputs)
#define DM 1024          // d_model
#define NS 16            // d_state
#define BSZ 8
#define LSEQ 1024
#define MROWS (BSZ*LSEQ) // 8192 token rows
#define CH 32            // scan chunk (timesteps staged per LDS buffer)
#define ROWP 36          // padded LDS row length (words), b128-aligned
#define YSP 18           // ys_p row pad (words), b64-aligned
#define NPAD 3328        // mega GEMM padded N (13 tiles of 256)

typedef __bf16 bf16;
typedef bf16 bf16x8 __attribute__((ext_vector_type(8)));
typedef bf16 bf16x4 __attribute__((ext_vector_type(4)));
typedef float f32x4 __attribute__((ext_vector_type(4)));
typedef float f32x2 __attribute__((ext_vector_type(2)));
typedef unsigned int u32;
typedef unsigned short u16;
typedef u32 u32x4 __attribute__((ext_vector_type(4)));

__device__ __forceinline__ void async16(const void* g, void* l) {
  __builtin_amdgcn_global_load_lds((const __attribute__((address_space(1))) void*)g,
                                   (__attribute__((address_space(3))) void*)l,
                                   16, 0, 0);
}

// packed (dt, xi) word: dt bf16 in low 16, xi bf16 in high 16
__device__ __forceinline__ float bflo(u32 u) { return __builtin_bit_cast(float, (u32)(u << 16)); }
__device__ __forceinline__ float bfhi(u32 u) { return __builtin_bit_cast(float, (u32)(u & 0xffff0000u)); }

// ---------------------------------------------------------------------------
// Fused preprocessing: weight casts + W_ig transpose + layernorm + wmega
// pad-row zero-fill in ONE launch. Block ranges:
//   [0,4128)       : f32->bf16 casts (5 weight tensors, float4-granular)
//   [4128,4384)    : W_ig[:1024]^T transpose+cast (64x64 LDS tiles)
//   [4384,12576)   : layernorm, one block per token row
//   [12576,12640)  : zero wmega rows [3200,3328) (mega N-pad; W reads defined)
// ---------------------------------------------------------------------------
__global__ __launch_bounds__(256)
void preproc(const float* __restrict__ W_ig, const float* __restrict__ W_dt,
             const float* __restrict__ W_B, const float* __restrict__ W_C,
             const float* __restrict__ W_out,
             bf16* __restrict__ wmega, bf16* __restrict__ wstack,
             bf16* __restrict__ wout, bf16* __restrict__ wigT,
             const float* __restrict__ x, const float* __restrict__ ln_g,
             const float* __restrict__ ln_b, bf16* __restrict__ xnorm) {
  __shared__ float tile[64][65];     // used by transpose range only
  const int blk = blockIdx.x;
  const int t = threadIdx.x;

  if (blk < 4128) {
    int i = blk * 256 + t;           // float4 index, total 1056768
    const float* s; bf16* d; int base;
    if (i < 524288)      { s = W_ig;  d = wmega;                           base = 0; }
    else if (i < 786432) { s = W_dt;  d = wstack;                          base = 524288; }
    else if (i < 790528) { s = W_B;   d = wstack + (size_t)DM * DM;        base = 786432; }
    else if (i < 794624) { s = W_C;   d = wstack + (size_t)(DM + NS) * DM; base = 790528; }
    else                 { s = W_out; d = wout;                            base = 794624; }
    int k = i - base;
    float4 v = ((const float4*)s)[k];
    bf16x4 o;
    o.x = (bf16)v.x; o.y = (bf16)v.y; o.z = (bf16)v.z; o.w = (bf16)v.w;
    *(bf16x4*)(d + 4 * (size_t)k) = o;
  } else if (blk < 4384) {
    int tb = blk - 4128;
    const int bk = (tb & 15) * 64;
    const int bd = (tb >> 4) * 64;
    const int c4 = t & 15;
    const int r0 = t >> 4;
#pragma unroll
    for (int p = 0; p < 4; ++p) {
      int r = r0 + p * 16;
      float4 v = *(const float4*)(W_ig + (size_t)(bd + r) * 1024 + bk + c4 * 4);
      tile[r][c4 * 4 + 0] = v.x;
      tile[r][c4 * 4 + 1] = v.y;
      tile[r][c4 * 4 + 2] = v.z;
      tile[r][c4 * 4 + 3] = v.w;
    }
    __syncthreads();
#pragma unroll
    for (int p = 0; p < 4; ++p) {
      int r = r0 + p * 16;
      bf16x4 o;
      o.x = (bf16)tile[c4 * 4 + 0][r];
      o.y = (bf16)tile[c4 * 4 + 1][r];
      o.z = (bf16)tile[c4 * 4 + 2][r];
      o.w = (bf16)tile[c4 * 4 + 3][r];
      *(bf16x4*)(wigT + (size_t)(bk + r) * 1024 + bd + c4 * 4) = o;
    }
  } else if (blk < 12576) {
    const size_t row = blk - 4384;
    float4 v = ((const float4*)(x + row * DM))[t];
    float s = v.x + v.y + v.z + v.w;
    float s2 = v.x*v.x + v.y*v.y + v.z*v.z + v.w*v.w;
#pragma unroll
    for (int m = 1; m < 64; m <<= 1) { s += __shfl_xor(s, m, 64); s2 += __shfl_xor(s2, m, 64); }
    __shared__ float red[8];
    int wave = t >> 6, lane = t & 63;
    if (lane == 0) { red[wave] = s; red[4 + wave] = s2; }
    __syncthreads();
    s  = red[0] + red[1] + red[2] + red[3];
    s2 = red[4] + red[5] + red[6] + red[7];
    float mu  = s * (1.f / DM);
    float var = s2 * (1.f / DM) - mu * mu;
    float inv = rsqrtf(var + 1e-5f);
    float4 gg = ((const float4*)ln_g)[t];
    float4 bb = ((const float4*)ln_b)[t];
    bf16x4 o;
    o.x = (bf16)((v.x - mu) * inv * gg.x + bb.x);
    o.y = (bf16)((v.y - mu) * inv * gg.y + bb.y);
    o.z = (bf16)((v.z - mu) * inv * gg.z + bb.z);
    o.w = (bf16)((v.w - mu) * inv * gg.w + bb.w);
    *(bf16x4*)(xnorm + row * DM + t * 4) = o;
  } else {
    // zero-fill wmega rows [3200, 3328): 131072 bf16 over 64 blocks
    size_t idx = (size_t)(blk - 12576) * 256 + t;
    bf16x8 z = {};
    *(bf16x8*)(wmega + (size_t)3200 * DM + idx * 8) = z;
  }
}

// ---------------------------------------------------------------------------
// 256x256 8-wave phase-split MFMA GEMM for the MEGA projection (T2+T3+T5
// port of the m201-class structure, adapted to this problem's 4-region
// epilogue). BM=BN=256, BK=64, 512 threads (8 waves, 2M x 4N), 2 LDS
// buffers (128KB, 1 block/CU). Per K-tile: 4 phases, each {ds-reads |
// stage next-tile half | barrier | setprio(1) 16 MFMA setprio(0) |
// barrier}; ONE exact vmcnt(0) per K-tile at phase 3 (stage-ahead-1:
// loads issued phases 0-2 get ~3 phases of latency cover).
// LDS swizzle: 8-chunk XOR permute phys = lc ^ ((row>>1)&7) -- read-side
// XOR is lane-constant (lr>>1)&7 (derivation in comments), giving 2
// lanes/bank (free). gload_lds dest is LINEAR; the global SOURCE is
// inverse-swizzled per lane (rule #21).
// ---------------------------------------------------------------------------
__global__ __launch_bounds__(512, 2)
void gemm256_mega(const bf16* __restrict__ A, const bf16* __restrict__ W,
                  bf16* __restrict__ out_z, u16* __restrict__ out_xi,
                  u16* __restrict__ out_dt, const float* __restrict__ aux,
                  float* __restrict__ out_B, float* __restrict__ out_C) {
  __shared__ bf16 As2[2][256 * 64];
  __shared__ bf16 Bs2[2][256 * 64];
  const int K = 1024;

  // bijective XCD swizzle: 416 blocks = 8 XCD x 52; within stripe n-major
  const int g = blockIdx.x;
  const int xcd = g & 7, local = g >> 3;      // local 0..51
  const int tx = local >> 2;                  // n-tile 0..12
  const int ty = xcd * 4 + (local & 3);       // m-tile 0..31

  const int tid = threadIdx.x;
  const int w = tid >> 6, lane = tid & 63;
  const int wm = w >> 2, wn = w & 3;          // wave grid 2M x 4N
  const int lr = lane & 15, quad = lane >> 4;
  const int swz = (lr >> 1) & 7;              // read-side chunk XOR (lane-const)
  const size_t arow = (size_t)ty * 256;
  const size_t brow = (size_t)tx * 256;

  f32x4 acc[8][4] = {};

  // staging: 2048 chunks (16B) per operand per K-tile; thread covers
  // chunk = w*64 + lane + s*512 for s=0..3. LDS holds chunk c at linear
  // elems [c*8, c*8+8); global source row = c>>3, k-chunk = (c&7) ^
  // ((row>>1)&7) (inverse swizzle).
  const bf16 *asrc0, *asrc1, *asrc2, *asrc3, *wsrc0, *wsrc1, *wsrc2, *wsrc3;
  {
#define SRC_INIT(s) {                                                   \
    int chunk = w * 64 + lane + (s) * 512;                              \
    int row = chunk >> 3;                                               \
    int logical = (chunk & 7) ^ ((row >> 1) & 7);                       \
    asrc##s = A + (arow + row) * (size_t)K + logical * 8;               \
    wsrc##s = W + (brow + row) * (size_t)K + logical * 8; }
    SRC_INIT(0) SRC_INIT(1) SRC_INIT(2) SRC_INIT(3)
#undef SRC_INIT
  }

#define STAGE256(buf, s, koff)                                           \
  do {                                                                   \
    async16(asrc##s + (koff), &As2[buf][0] + ((s) * 512 + w * 64) * 8);  \
    async16(wsrc##s + (koff), &Bs2[buf][0] + ((s) * 512 + w * 64) * 8);  \
  } while (0)

  // A-frag read: frag fi (row wm*128+fi*16+lr), ksub s: elem offset =
  // row*64 + ((s*4+quad)^swz)*8.  ((row>>1)&7)==swz because wm*128+fi*16
  // is a multiple of 16 (>>1 gives multiple of 8, ==0 mod 8).
#define RD_A(bufp, mh, af)                                               \
  _Pragma("unroll")                                                      \
  for (int i = 0; i < 4; ++i) {                                          \
    _Pragma("unroll")                                                    \
    for (int s = 0; s < 2; ++s)                                          \
      af[i][s] = *(const bf16x8*)((bufp) +                               \
        (wm * 128 + ((mh) * 4 + i) * 16 + lr) * 64 +                     \
        ((s * 4 + quad) ^ swz) * 8);                                     \
  }
#define RD_B(bufp, bfr)                                                  \
  _Pragma("unroll")                                                      \
  for (int j = 0; j < 4; ++j) {                                          \
    _Pragma("unroll")                                                    \
    for (int s = 0; s < 2; ++s)                                          \
      bfr[j][s] = *(const bf16x8*)((bufp) +                              \
        (wn * 64 + j * 16 + lr) * 64 +                                   \
        ((s * 4 + quad) ^ swz) * 8);                                     \
  }
#define MMQ(af, bfr, mh, nh)                                             \
  do {                                                                   \
    __builtin_amdgcn_s_setprio(1);                                       \
    _Pragma("unroll")                                                    \
    for (int i = 0; i < 4; ++i)                                          \
      _Pragma("unroll")                                                  \
      for (int jj = 0; jj < 2; ++jj)                                     \
        _Pragma("unroll")                                                \
        for (int s = 0; s < 2; ++s)                                      \
          acc[(mh) * 4 + i][(nh) * 2 + jj] =                             \
            __builtin_amdgcn_mfma_f32_16x16x32_bf16(                     \
              af[i][s], bfr[(nh) * 2 + jj][s],                           \
              acc[(mh) * 4 + i][(nh) * 2 + jj], 0, 0, 0);                \
    __builtin_amdgcn_s_setprio(0);                                       \
  } while (0)

  // prologue: stage K-tile 0 into buffer 0, drain, sync
  STAGE256(0, 0, 0); STAGE256(0, 1, 0); STAGE256(0, 2, 0); STAGE256(0, 3, 0);
  asm volatile("s_waitcnt vmcnt(0)" ::: "memory");
  __builtin_amdgcn_s_barrier();

  for (int kt = 0; kt < 16; ++kt) {
    const int buf = kt & 1, nbuf = buf ^ 1;
    const int koff = (kt + 1) * 64;          // next tile's k elem offset
    const bf16* Ab = buf ? &As2[1][0] : &As2[0][0];
    const bf16* Bb = buf ? &Bs2[1][0] : &Bs2[0][0];
    const bool pf = (kt < 15);
    bf16x8 af[4][2], bfr[4][2];

    // phase 0: read A(m-half0) + B(all); stage s0,s1 of next tile
    RD_A(Ab, 0, af)
    RD_B(Bb, bfr)
    if (pf) { if (nbuf) { STAGE256(1, 0, koff); STAGE256(1, 1, koff); }
              else      { STAGE256(0, 0, koff); STAGE256(0, 1, koff); } }
    __builtin_amdgcn_s_barrier();
    MMQ(af, bfr, 0, 0);
    __builtin_amdgcn_s_barrier();

    // phase 1: stage s2
    if (pf) { if (nbuf) STAGE256(1, 2, koff); else STAGE256(0, 2, koff); }
    __builtin_amdgcn_s_barrier();
    MMQ(af, bfr, 0, 1);
    __builtin_amdgcn_s_barrier();

    // phase 2: read A(m-half1); stage s3
    RD_A(Ab, 1, af)
    if (pf) { if (nbuf) STAGE256(1, 3, koff); else STAGE256(0, 3, koff); }
    __builtin_amdgcn_s_barrier();
    MMQ(af, bfr, 1, 1);
    __builtin_amdgcn_s_barrier();

    // phase 3: exact drain (all 8 next-tile loads issued by phase 2)
    asm volatile("s_waitcnt vmcnt(0)" ::: "memory");
    __builtin_amdgcn_s_barrier();
    MMQ(af, bfr, 1, 0);
    __builtin_amdgcn_s_barrier();
  }

  // Epilogue: per-wave rows [mb,mb+128), cols [nb,nb+64). Region split as
  // the 128^2 kernel (wave col-span is 64, boundaries are 1024-aligned).
  // tiled-16 outputs LDS-staged dense (R8): per j stage 128x16 then store
  // 128 rows x 32B contiguous.
  const size_t mb = arow + (size_t)wm * 128;
  const size_t nb = brow + (size_t)wn * 64;
  if (nb < 3 * DM) {
    u16* dst; size_t gbase; bool is_dt = false;
    if (nb < DM)          { dst = out_xi;      gbase = nb >> 4; }
    else if (nb < 2 * DM) { dst = (u16*)out_z; gbase = (nb - DM) >> 4; }
    else                  { dst = out_dt;      gbase = (nb - 2 * DM) >> 4; is_dt = true; }
    bf16* lds_ep = &As2[0][0] + (size_t)w * 2048;   // 4KB private slice
#pragma unroll
    for (int j = 0; j < 4; ++j) {
#pragma unroll
      for (int i = 0; i < 8; ++i)
#pragma unroll
        for (int r = 0; r < 4; ++r) {
          float v = acc[i][j][r];
          if (is_dt) {
            float tt = v + aux[nb - 2 * DM + j * 16 + lr];
            v = (tt > 20.f) ? tt : __logf(1.f + __expf(tt));
          }
          lds_ep[(i * 16 + quad * 4 + r) * 16 + lr] = (bf16)v;
        }
#pragma unroll
      for (int rr = 0; rr < 2; ++rr) {
        int row = rr * 64 + lane;
        u32x4 v0 = *(u32x4*)&lds_ep[row * 16];
        u32x4 v1 = *(u32x4*)&lds_ep[row * 16 + 8];
        size_t off = ((gbase + j) * (size_t)MROWS + mb + row) * 16;
        *(u32x4*)&dst[off]     = v0;
        *(u32x4*)&dst[off + 8] = v1;
      }
    }
  } else if (nb < 3 * DM + 2 * NS) {   // B/C wave (j==0 -> B, j==1 -> C)
#pragma unroll
    for (int i = 0; i < 8; ++i)
#pragma unroll
      for (int r = 0; r < 4; ++r) {
        size_t m = mb + i * 16 + quad * 4 + r;
        out_B[m * NS + lr] = acc[i][0][r];
        out_C[m * NS + lr] = acc[i][1][r];
      }
  } // else: pad columns, discard
#undef STAGE256
#undef RD_A
#undef RD_B
#undef MMQ
}

// ---------------------------------------------------------------------------
// 128x128 MFMA bf16 GEMM (R8/R9-proven depth-3 counted-vmcnt pipeline) for
// the compose (EPI==3) and output (EPI==2) GEMMs. [R10: do not deepen --
// occupancy beats pipeline depth at this tile.]
// ---------------------------------------------------------------------------
template <int EPI, bool SWZ>
__global__ __launch_bounds__(256)
void gemm_bf16(const bf16* __restrict__ A, const bf16* __restrict__ W, int K,
               float* __restrict__ out_f, bf16* __restrict__ out_b,
               const float* __restrict__ aux) {
  __shared__ bf16 As[3][128 * 32];
  __shared__ bf16 Bs[3][128 * 32];
  int tx, ty;
  if (SWZ) {
    int g = blockIdx.x;
    int xcd = g & 7, slot = g >> 3;
    tx = slot >> 3;
    ty = xcd * 8 + (slot & 7);
  } else {
    tx = blockIdx.x; ty = blockIdx.y;
  }
  const int tid  = threadIdx.x;
  const int wave = tid >> 6, lane = tid & 63;
  const int lr = lane & 15, quad = lane >> 4;
  const size_t arow = (size_t)ty * 128;
  const size_t brow = (size_t)tx * 128;
  f32x4 acc[4][4] = {};

  const int srl  = lane >> 2;
  const int kg   = lane & 3;
  const int srow = wave * 32 + srl;
  const int skc  = (kg ^ ((srl >> 1) & 3)) * 8;
  const bf16* ag = A + (arow + srow) * (size_t)K + skc;
  const bf16* wg = W + (brow + srow) * (size_t)K + skc;

  const int soff = wave * 32 * 32;
  const int ra   = (((wave >> 1) * 64) + lr) * 32 + ((quad ^ ((lr >> 1) & 3)) * 8);
  const int rb   = (((wave & 1)  * 64) + lr) * 32 + ((quad ^ ((lr >> 1) & 3)) * 8);

  bf16 *aw0 = &As[0][soff], *aw1 = &As[1][soff], *aw2 = &As[2][soff];
  bf16 *bw0 = &Bs[0][soff], *bw1 = &Bs[1][soff], *bw2 = &Bs[2][soff];
  const bf16 *ar0 = &As[0][ra], *ar1 = &As[1][ra], *ar2 = &As[2][ra];
  const bf16 *br0 = &Bs[0][rb], *br1 = &Bs[1][rb], *br2 = &Bs[2][rb];

  auto STAGE = [&](bf16* adst, bf16* bdst, int kk) {
    async16(ag + kk,                       adst);
    async16(ag + (size_t)16 * K + kk,      adst + 16 * 32);
    async16(wg + kk,                       bdst);
    async16(wg + (size_t)16 * K + kk,      bdst + 16 * 32);
  };
  auto COMPUTE = [&](const bf16* ap, const bf16* bp) {
    bf16x8 af[4], bfr[4];
#pragma unroll
    for (int i = 0; i < 4; ++i) af[i] = *(const bf16x8*)(ap + i * 16 * 32);
#pragma unroll
    for (int j = 0; j < 4; ++j) bfr[j] = *(const bf16x8*)(bp + j * 16 * 32);
#pragma unroll
    for (int i = 0; i < 4; ++i)
#pragma unroll
      for (int j = 0; j < 4; ++j)
        acc[i][j] = __builtin_amdgcn_mfma_f32_16x16x32_bf16(af[i], bfr[j], acc[i][j], 0, 0, 0);
  };

  STAGE(aw0, bw0, 0);
  STAGE(aw1, bw1, 32);
  asm volatile("s_waitcnt vmcnt(4)" ::: "memory");
  __builtin_amdgcn_s_barrier();

  for (int k0 = 0; k0 < K; k0 += 32) {
    const bool pf = (k0 + 64 < K);
    if (pf) STAGE(aw2, bw2, k0 + 64);
    COMPUTE(ar0, br0);
    if (pf) asm volatile("s_waitcnt vmcnt(4)" ::: "memory");
    else    asm volatile("s_waitcnt vmcnt(0)" ::: "memory");
    __builtin_amdgcn_s_barrier();
    bf16* t0;
    t0 = aw0; aw0 = aw1; aw1 = aw2; aw2 = t0;
    t0 = bw0; bw0 = bw1; bw1 = bw2; bw2 = t0;
    const bf16* t1;
    t1 = ar0; ar0 = ar1; ar1 = ar2; ar2 = t1;
    t1 = br0; br0 = br1; br1 = br2; br2 = t1;
  }

  const size_t mbase = arow + (wave >> 1) * 64;
  const size_t nbase = brow + (wave & 1) * 64;
#pragma unroll
  for (int i = 0; i < 4; ++i)
#pragma unroll
    for (int j = 0; j < 4; ++j)
#pragma unroll
      for (int r = 0; r < 4; ++r) {
        size_t m = mbase + i * 16 + quad * 4 + r;
        size_t n = nbase + j * 16 + lr;
        float v = acc[i][j][r];
        if (EPI == 2) {
          out_f[m * DM + n] = v + aux[m * DM + n];
        } else {
          out_b[m * (size_t)DM + n] = (bf16)v;
        }
      }
}

// ---------------------------------------------------------------------------
// Selective scan + fused gate, v8 (R11-verified). Tiled-16 dt/xi/z + ys_p
// LDS n-reduction. Paired staging loads; phase-2 b64 reads.
// ---------------------------------------------------------------------------
__global__ __launch_bounds__(256)
void scan_kernel(const u16* __restrict__ dt_b, const u16* __restrict__ xi_b,
                 const bf16* __restrict__ z_b,
                 const float* __restrict__ B_t, const float* __restrict__ C_t,
                 const float* __restrict__ A_log, const float* __restrict__ h_prev,
                 const float* __restrict__ Dvec,
                 bf16* __restrict__ ssm_out, float* __restrict__ h_final) {
  const int blk = blockIdx.x;        // 512 blocks
  const int b = blk >> 6;
  const int g = blk & 63;            // channel group
  const int d0 = g * 16;
  const int t = threadIdx.x;
  const int n = t & 15, dl = t >> 4;
  const int d = d0 + dl;
  const float Ac2 = -__expf(A_log[d * NS + n]) * 1.44269504f;
  float h = h_prev[(size_t)b * DM * NS + (size_t)d * NS + n];

  __shared__ u32   dxs[2][16][ROWP];
  __shared__ float Bsh[2][16][ROWP];
  __shared__ float Csh[2][16][ROWP];
  __shared__ float ys_p[CH][16][YSP];

  const size_t base_row = (size_t)b * LSEQ;
  const size_t base16 = ((size_t)g * MROWS + base_row) * 16;
  const int pl = t >> 3, pc = (2 * t) & 15;
  const int l_a = t >> 4, c_a = t & 15;
  const float Dva = Dvec[d0 + c_a];

  {
    u32 D = ((const u32*)(dt_b + base16))[t];
    u32 X = ((const u32*)(xi_b + base16))[t];
    dxs[0][pc][pl]     = (D & 0xffffu) | (X << 16);
    dxs[0][pc + 1][pl] = (D >> 16) | (X & 0xffff0000u);
    size_t gB = base_row * NS;
    f32x2 B2 = ((const f32x2*)(B_t + gB))[t];
    f32x2 C2 = ((const f32x2*)(C_t + gB))[t];
    Bsh[0][pc][pl] = B2.x;  Bsh[0][pc + 1][pl] = B2.y;
    Csh[0][pc][pl] = C2.x;  Csh[0][pc + 1][pl] = C2.y;
  }
  float za = (float)z_b[base16 + t];
  float zb = (float)z_b[base16 + 256 + t];
  __syncthreads();

  for (int c = 0; c < LSEQ / CH; ++c) {
    const int cur = c & 1, nxt = cur ^ 1;
    u32 pD, pX; f32x2 pB2, pC2; float pza, pzb;
    if (c + 1 < LSEQ / CH) {
      size_t off = base16 + (size_t)(c + 1) * (CH * 16);
      pD = ((const u32*)(dt_b + off))[t];
      pX = ((const u32*)(xi_b + off))[t];
      pza = (float)z_b[off + t]; pzb = (float)z_b[off + 256 + t];
      size_t gB = (base_row + (size_t)(c + 1) * CH) * NS;
      pB2 = ((const f32x2*)(B_t + gB))[t];
      pC2 = ((const f32x2*)(C_t + gB))[t];
    }
#pragma unroll
    for (int l4 = 0; l4 < CH; l4 += 4) {
      u32x4 dx4 = *(const u32x4*)&dxs[cur][dl][l4];
      f32x4 b4  = *(const f32x4*)&Bsh[cur][n][l4];
      f32x4 c4  = *(const f32x4*)&Csh[cur][n][l4];
#pragma unroll
      for (int i = 0; i < 4; ++i) {
        float dtv = bflo(dx4[i]), xiv = bfhi(dx4[i]);
        float a = __builtin_amdgcn_exp2f(dtv * Ac2);
        h = fmaf(a, h, (dtv * xiv) * b4[i]);
        ys_p[l4 + i][dl][n] = h * c4[i];
      }
    }
    __syncthreads();
    {
      const f32x2* r1 = (const f32x2*)&ys_p[l_a][c_a][0];
      const f32x2* r2 = (const f32x2*)&ys_p[l_a + 16][c_a][0];
      float s1 = 0.f, s2 = 0.f;
#pragma unroll
      for (int k = 0; k < 8; ++k) {
        f32x2 v1 = r1[k], v2 = r2[k];
        s1 += v1.x + v1.y;
        s2 += v2.x + v2.y;
      }
      float x1 = bfhi(dxs[cur][c_a][l_a]);
      float x2 = bfhi(dxs[cur][c_a][l_a + 16]);
      float g1 = za / (1.f + __expf(-za));
      float g2 = zb / (1.f + __expf(-zb));
      size_t l0 = (size_t)c * CH;
      ssm_out[(base_row + l0 + l_a) * DM + d0 + c_a]      = (bf16)(s1 * g1 + x1 * Dva);
      ssm_out[(base_row + l0 + l_a + 16) * DM + d0 + c_a] = (bf16)(s2 * g2 + x2 * Dva);
    }
    if (c + 1 < LSEQ / CH) {
      dxs[nxt][pc][pl]     = (pD & 0xffffu) | (pX << 16);
      dxs[nxt][pc + 1][pl] = (pD >> 16) | (pX & 0xffff0000u);
      Bsh[nxt][pc][pl] = pB2.x;  Bsh[nxt][pc + 1][pl] = pB2.y;
      Csh[nxt][pc][pl] = pC2.x;  Csh[nxt][pc + 1][pl] = pC2.y;
      za = pza; zb = pzb;
    }
    __syncthreads();
  }
  h_final[(size_t)b * DM * NS + (size_t)d0 * NS + t] = h;
}

// ---------------------------------------------------------------------------
extern "C" void kernel_launch(void* const* d_in, const int* in_sizes, int n_in,
                              void* d_out, int out_size, void* d_ws, size_t ws_size,
                              hipStream_t stream) {
  const float* x      = (const float*)d_in[0];
  const float* h_prev = (const float*)d_in[1];
  const float* ln_g   = (const float*)d_in[2];
  const float* ln_b   = (const float*)d_in[3];
  const float* W_ig   = (const float*)d_in[4];
  const float* W_dt   = (const float*)d_in[5];
  const float* b_dt   = (const float*)d_in[6];
  const float* A_log  = (const float*)d_in[7];
  const float* W_B    = (const float*)d_in[8];
  const float* W_C    = (const float*)d_in[9];
  const float* Dvec   = (const float*)d_in[10];
  const float* W_out  = (const float*)d_in[11];

  char* ws = (char*)d_ws;
  size_t off = 0;
  auto alloc = [&](size_t bytes) -> char* {
    char* p = ws + off;
    off += (bytes + 255) & ~(size_t)255;
    return p;
  };
  bf16*  wmega_b = (bf16*)alloc((size_t)NPAD * DM * 2);       // 6.5 MB (3328 rows)
  bf16*  wstack_b= (bf16*)alloc((size_t)1152 * DM * 2);       // 2.25 MB
  bf16*  wigT_b  = (bf16*)alloc((size_t)DM * DM * 2);         // 2 MB
  bf16*  wout_b  = (bf16*)alloc((size_t)DM * DM * 2);         // 2 MB
  bf16*  xnorm_b = (bf16*)alloc((size_t)MROWS * DM * 2);      // 16 MB
  u16*   xi_w    = (u16*)alloc((size_t)MROWS * DM * 2);       // 16 MB (tiled-16)
  u16*   dt_w    = (u16*)alloc((size_t)MROWS * DM * 2);       // 16 MB (tiled-16)
  bf16*  z_bb    = (bf16*)alloc((size_t)MROWS * DM * 2);      // 16 MB (tiled-16)
  bf16*  ssm_b   = (bf16*)alloc((size_t)MROWS * DM * 2);      // 16 MB
  float* Bt      = (float*)alloc((size_t)MROWS * NS * 4);     // 0.5 MB
  float* Ct      = (float*)alloc((size_t)MROWS * NS * 4);     // 0.5 MB
  (void)ws_size; (void)in_sizes; (void)n_in; (void)out_size;

  float* out_main = (float*)d_out;
  float* out_h    = (float*)d_out + (size_t)MROWS * DM;

  // 1) fused preprocessing: casts + transpose + layernorm + pad zero-fill
  preproc<<<12640, 256, 0, stream>>>(W_ig, W_dt, W_B, W_C, W_out,
                                     wmega_b, wstack_b, wout_b, wigT_b,
                                     x, ln_g, ln_b, xnorm_b);

  // 2) compose: wmega[2048+e][k] = sum_d [Wdt;WB;WC][e][d] * W_ig[d][k]
  gemm_bf16<3, false><<<dim3(8, 9), 256, 0, stream>>>(wstack_b, wigT_b, DM,
      nullptr, wmega_b + (size_t)2048 * DM, nullptr);

  // 3) mega GEMM (M=8192, N=3328 pad, K=1024), 256^2 8-wave phase-split:
  //    writes xi, z, dt (tiled-16 via LDS-staged dense stores), B_t, C_t
  gemm256_mega<<<416, 512, 0, stream>>>(xnorm_b, wmega_b,
      z_bb, xi_w, dt_w, b_dt, Bt, Ct);

  // 4) selective scan + fused gate -> ssm_b, h_final
  scan_kernel<<<512, 256, 0, stream>>>(dt_w, xi_w, z_bb, Bt, Ct, A_log, h_prev,
                                       Dvec, ssm_b, out_h);

  // 5) output GEMM (M=8192, N=1024, K=1024) + residual x, XCD-swizzled
  gemm_bf16<2, true><<<512, 256, 0, stream>>>(ssm_b, wout_b, DM,
      out_main, nullptr, x);
}